// Round 3
// baseline (870.054 us; speedup 1.0000x reference)
//
#include <hip/hip_runtime.h>

#define N_NODES 100000
#define N_EDGES 1600000
#define DIM 64
#define NB ((N_NODES + 63) / 64)   // 1563 buckets of 64 nodes

// ===========================================================================
// Sorted-bucket path
// ===========================================================================

__global__ void zero_u32(unsigned* __restrict__ p, int n) {
    int i = blockIdx.x * blockDim.x + threadIdx.x;
    if (i < n) p[i] = 0u;
}

// Histogram of dst buckets, LDS-privatized (6.25 KB), flush via global atomics.
__global__ void hist_kernel(const int* __restrict__ dst, unsigned* __restrict__ cnt) {
    __shared__ unsigned lh[NB];
    for (int i = threadIdx.x; i < NB; i += blockDim.x) lh[i] = 0u;
    __syncthreads();
    int stride = gridDim.x * blockDim.x;
    for (int e = blockIdx.x * blockDim.x + threadIdx.x; e < N_EDGES; e += stride)
        atomicAdd(&lh[((unsigned)dst[e]) >> 6], 1u);
    __syncthreads();
    for (int i = threadIdx.x; i < NB; i += blockDim.x) {
        unsigned v = lh[i];
        if (v) atomicAdd(&cnt[i], v);
    }
}

// Exclusive scan of cnt[NB] -> off[NB+1]; also init cursor = off.
// Single block, 1024 threads, Hillis-Steele over 2048-padded array.
__global__ void scan_kernel(const unsigned* __restrict__ cnt,
                            unsigned* __restrict__ off,
                            unsigned* __restrict__ cursor) {
    __shared__ unsigned s[2048];
    int t = threadIdx.x;
    s[t]        = (t < NB)        ? cnt[t]        : 0u;
    s[t + 1024] = (t + 1024 < NB) ? cnt[t + 1024] : 0u;
    __syncthreads();
    for (int o = 1; o < 2048; o <<= 1) {
        unsigned a0 = s[t];
        unsigned a1 = s[t + 1024];
        unsigned b0 = (t >= o) ? s[t - o] : 0u;
        unsigned b1 = (t + 1024 >= o) ? s[t + 1024 - o] : 0u;
        __syncthreads();
        s[t] = a0 + b0;
        s[t + 1024] = a1 + b1;
        __syncthreads();
    }
    for (int i = t; i <= NB; i += 1024) {
        unsigned v = (i == 0) ? 0u : s[i - 1];
        off[i] = v;
        if (i < NB) cursor[i] = v;
    }
}

// Scatter edges into bucket-sorted order. Packed: word0 = src | dstlocal<<17
// (src < 131072 fits 17 bits), word1 = bits of w.
__global__ void scatter_sort_kernel(const int* __restrict__ src,
                                    const int* __restrict__ dst,
                                    const float* __restrict__ w,
                                    unsigned* __restrict__ cursor,
                                    uint2* __restrict__ srt) {
    int stride = gridDim.x * blockDim.x;
    for (int e = blockIdx.x * blockDim.x + threadIdx.x; e < N_EDGES; e += stride) {
        unsigned d = (unsigned)dst[e];
        unsigned b = d >> 6;
        unsigned pos = atomicAdd(&cursor[b], 1u);
        srt[pos] = make_uint2((unsigned)src[e] | ((d & 63u) << 17),
                              __float_as_uint(w[e]));
    }
}

// One block per bucket: accumulate h[64][64] in LDS (ds_add_f32), then apply
// the linear (W column held in 64 VGPRs per lane) and store final out rows.
__global__ __launch_bounds__(256, 4) void fused_kernel(
        const float* __restrict__ feat, const uint2* __restrict__ srt,
        const unsigned* __restrict__ off, const float* __restrict__ W,
        const float* __restrict__ bias, float* __restrict__ out) {
    __shared__ float h[64 * DIM];   // 16 KB
    int tid = threadIdx.x, lane = tid & 63, wv = tid >> 6;

    for (int i = tid; i < 64 * DIM; i += 256) h[i] = 0.f;

    // W column `lane` into registers (reused for all 64 rows of this bucket)
    float Wreg[DIM];
#pragma unroll
    for (int k = 0; k < DIM; ++k) Wreg[k] = W[k * DIM + lane];
    float bv = bias[lane];
    __syncthreads();

    int b = blockIdx.x;
    int base = (int)off[b], end = (int)off[b + 1];

    // Edge accumulate: each wave takes chunks of 4 edges; 4 gathers in flight.
    for (int e = base + wv * 4; e < end; e += 16) {
        int n = end - e; if (n > 4) n = 4;
        uint2 u0 = srt[e];
        uint2 u1 = (n > 1) ? srt[e + 1] : u0;
        uint2 u2 = (n > 2) ? srt[e + 2] : u0;
        uint2 u3 = (n > 3) ? srt[e + 3] : u0;
        float f0 = feat[(u0.x & 0x1FFFFu) * DIM + lane] * __uint_as_float(u0.y);
        float f1 = feat[(u1.x & 0x1FFFFu) * DIM + lane] * __uint_as_float(u1.y);
        float f2 = feat[(u2.x & 0x1FFFFu) * DIM + lane] * __uint_as_float(u2.y);
        float f3 = feat[(u3.x & 0x1FFFFu) * DIM + lane] * __uint_as_float(u3.y);
        atomicAdd(&h[((u0.x >> 17) & 63u) * DIM + lane], f0);
        if (n > 1) atomicAdd(&h[((u1.x >> 17) & 63u) * DIM + lane], f1);
        if (n > 2) atomicAdd(&h[((u2.x >> 17) & 63u) * DIM + lane], f2);
        if (n > 3) atomicAdd(&h[((u3.x >> 17) & 63u) * DIM + lane], f3);
    }
    __syncthreads();

    // Linear: wave wv handles nodes wv, wv+4, ...; h row read as uniform b128.
    int rowbase = b * 64;
    for (int n = wv; n < 64; n += 4) {
        float acc = bv;
#pragma unroll
        for (int k = 0; k < DIM; k += 4) {
            float4 hk = *reinterpret_cast<float4*>(&h[n * DIM + k]);
            acc = fmaf(hk.x, Wreg[k + 0], acc);
            acc = fmaf(hk.y, Wreg[k + 1], acc);
            acc = fmaf(hk.z, Wreg[k + 2], acc);
            acc = fmaf(hk.w, Wreg[k + 3], acc);
        }
        int row = rowbase + n;
        if (row < N_NODES) out[(long)row * DIM + lane] = acc;
    }
}

// ===========================================================================
// Fallback path (round-0 kernels) if workspace is too small
// ===========================================================================

__global__ void zero_kernel(float4* __restrict__ p, int n4) {
    int stride = gridDim.x * blockDim.x;
    for (int i = blockIdx.x * blockDim.x + threadIdx.x; i < n4; i += stride)
        p[i] = float4{0.f, 0.f, 0.f, 0.f};
}

__global__ void scatter_kernel(const float* __restrict__ feat,
                               const float* __restrict__ edge_w,
                               const int* __restrict__ src,
                               const int* __restrict__ dst,
                               float* __restrict__ h, int n_edges) {
    int lane = threadIdx.x & 63;
    int wave = (int)((blockIdx.x * blockDim.x + threadIdx.x) >> 6);
    int total_waves = (int)((gridDim.x * blockDim.x) >> 6);
    for (int e = wave; e < n_edges; e += total_waves) {
        int s = src[e], d = dst[e];
        float v = feat[(long)s * DIM + lane] * edge_w[e];
        atomicAdd(&h[(long)d * DIM + lane], v);
    }
}

__global__ void linear_kernel(float* __restrict__ h, const float* __restrict__ W,
                              const float* __restrict__ bias, int n_nodes) {
    __shared__ float Ws[DIM * DIM];
    __shared__ float bs[DIM];
    for (int i = threadIdx.x; i < DIM * DIM; i += blockDim.x) Ws[i] = W[i];
    if (threadIdx.x < DIM) bs[threadIdx.x] = bias[threadIdx.x];
    __syncthreads();
    int lane = threadIdx.x & 63;
    int gwave = blockIdx.x * (blockDim.x >> 6) + (threadIdx.x >> 6);
    int total_waves = gridDim.x * (blockDim.x >> 6);
    for (int row = gwave; row < n_nodes; row += total_waves) {
        float hval = h[(long)row * DIM + lane];
        float acc = bs[lane];
#pragma unroll
        for (int k = 0; k < DIM; ++k)
            acc = fmaf(__shfl(hval, k, 64), Ws[k * DIM + lane], acc);
        h[(long)row * DIM + lane] = acc;
    }
}

// ===========================================================================
extern "C" void kernel_launch(void* const* d_in, const int* in_sizes, int n_in,
                              void* d_out, int out_size, void* d_ws, size_t ws_size,
                              hipStream_t stream) {
    const float* feat   = (const float*)d_in[0];
    const float* edge_w = (const float*)d_in[1];
    const int*   src    = (const int*)d_in[2];
    const int*   dst    = (const int*)d_in[3];
    const float* weight = (const float*)d_in[4];
    const float* bias   = (const float*)d_in[5];
    float* out = (float*)d_out;

    size_t needed = (size_t)N_EDGES * 8 + (size_t)(3 * NB + 1) * 4;
    if (ws_size >= needed) {
        uint2*    srt    = (uint2*)d_ws;
        unsigned* cnt    = (unsigned*)((char*)d_ws + (size_t)N_EDGES * 8);
        unsigned* off    = cnt + NB;
        unsigned* cursor = off + NB + 1;

        zero_u32<<<(NB + 255) / 256, 256, 0, stream>>>(cnt, NB);
        hist_kernel<<<256, 256, 0, stream>>>(dst, cnt);
        scan_kernel<<<1, 1024, 0, stream>>>(cnt, off, cursor);
        scatter_sort_kernel<<<1024, 256, 0, stream>>>(src, dst, edge_w, cursor, srt);
        fused_kernel<<<NB, 256, 0, stream>>>(feat, srt, off, weight, bias, out);
    } else {
        int n4 = N_NODES * DIM / 4;
        zero_kernel<<<2048, 256, 0, stream>>>((float4*)out, n4);
        scatter_kernel<<<2048, 256, 0, stream>>>(feat, edge_w, src, dst, out, N_EDGES);
        linear_kernel<<<2048, 256, 0, stream>>>(out, weight, bias, N_NODES);
    }
}

// Round 4
// 372.090 us; speedup vs baseline: 2.3383x; 2.3383x over previous
//
#include <hip/hip_runtime.h>

#define N_NODES 100000
#define N_EDGES 1600000
#define DIM 64

#define SCAN_BLK 2048
#define NSCAN ((N_NODES + 1 + SCAN_BLK - 1) / SCAN_BLK)   // 49 blocks

// ===========================================================================
// CSR pull path: hist -> scan -> scatter(sort by dst) -> fused pull+linear
// ===========================================================================

__global__ void zero_u32(unsigned* __restrict__ p, int n) {
    int i = blockIdx.x * blockDim.x + threadIdx.x;
    if (i < n) p[i] = 0u;
}

// Per-node degree histogram: 1.6M atomics over 100K counters (~16/counter).
__global__ void hist_kernel(const int* __restrict__ dst, unsigned* __restrict__ cnt) {
    int stride = gridDim.x * blockDim.x;
    for (int e = blockIdx.x * blockDim.x + threadIdx.x; e < N_EDGES; e += stride)
        atomicAdd(&cnt[dst[e]], 1u);
}

// Block-local inclusive scan (2048/block) -> exclusive within block + partials.
__global__ void scan1_kernel(const unsigned* __restrict__ cnt,
                             unsigned* __restrict__ off,
                             unsigned* __restrict__ partials) {
    __shared__ unsigned s[SCAN_BLK];
    int t = threadIdx.x;
    int base = blockIdx.x * SCAN_BLK;
    int i0 = base + t, i1 = base + t + 1024;
    s[t]        = (i0 < N_NODES) ? cnt[i0] : 0u;
    s[t + 1024] = (i1 < N_NODES) ? cnt[i1] : 0u;
    __syncthreads();
    for (int o = 1; o < SCAN_BLK; o <<= 1) {
        unsigned a0 = s[t];
        unsigned a1 = s[t + 1024];
        unsigned b0 = (t >= o) ? s[t - o] : 0u;
        unsigned b1 = (t + 1024 >= o) ? s[t + 1024 - o] : 0u;
        __syncthreads();
        s[t] = a0 + b0;
        s[t + 1024] = a1 + b1;
        __syncthreads();
    }
    for (int i = t; i < SCAN_BLK; i += 1024) {
        int g = base + i;
        if (g <= N_NODES) off[g] = (i == 0) ? 0u : s[i - 1];
    }
    if (t == 0) partials[blockIdx.x] = s[SCAN_BLK - 1];
}

// Serial exclusive scan of the 49 block partials.
__global__ void scan2_kernel(unsigned* __restrict__ partials) {
    if (threadIdx.x == 0 && blockIdx.x == 0) {
        unsigned run = 0;
        for (int b = 0; b < NSCAN; ++b) {
            unsigned v = partials[b];
            partials[b] = run;
            run += v;
        }
    }
}

// Add block offsets; init cursor = off.
__global__ void scan3_kernel(unsigned* __restrict__ off,
                             const unsigned* __restrict__ partials,
                             unsigned* __restrict__ cursor) {
    int i = blockIdx.x * blockDim.x + threadIdx.x;
    if (i <= N_NODES) {
        unsigned v = off[i] + partials[i / SCAN_BLK];
        off[i] = v;
        if (i < N_NODES) cursor[i] = v;
    }
}

// Scatter edges into dst-sorted order: srt[pos] = {src, w_bits}.
__global__ void scatter_sort_kernel(const int* __restrict__ src,
                                    const int* __restrict__ dst,
                                    const float* __restrict__ w,
                                    unsigned* __restrict__ cursor,
                                    uint2* __restrict__ srt) {
    int stride = gridDim.x * blockDim.x;
    for (int e = blockIdx.x * blockDim.x + threadIdx.x; e < N_EDGES; e += stride) {
        unsigned pos = atomicAdd(&cursor[dst[e]], 1u);
        srt[pos] = make_uint2((unsigned)src[e], __float_as_uint(w[e]));
    }
}

// One wave per node: register-accumulate h (no atomics), then apply the
// 64x64 linear in-wave (W column in VGPRs, h[k] broadcast via shfl).
__global__ __launch_bounds__(256) void pull_kernel(
        const float* __restrict__ feat, const uint2* __restrict__ srt,
        const unsigned* __restrict__ off, const float* __restrict__ W,
        const float* __restrict__ bias, float* __restrict__ out) {
    int lane = threadIdx.x & 63;
    float Wreg[DIM];
#pragma unroll
    for (int k = 0; k < DIM; ++k) Wreg[k] = W[k * DIM + lane];
    float bv = bias[lane];

    int gwave = (int)((blockIdx.x * blockDim.x + threadIdx.x) >> 6);
    int nwaves = (int)((gridDim.x * blockDim.x) >> 6);

    for (int v = gwave; v < N_NODES; v += nwaves) {
        int beg = (int)off[v], end = (int)off[v + 1];
        float acc = 0.f;
        int e = beg;
        for (; e + 4 <= end; e += 4) {
            uint2 u0 = srt[e + 0];
            uint2 u1 = srt[e + 1];
            uint2 u2 = srt[e + 2];
            uint2 u3 = srt[e + 3];
            float f0 = feat[u0.x * DIM + lane] * __uint_as_float(u0.y);
            float f1 = feat[u1.x * DIM + lane] * __uint_as_float(u1.y);
            float f2 = feat[u2.x * DIM + lane] * __uint_as_float(u2.y);
            float f3 = feat[u3.x * DIM + lane] * __uint_as_float(u3.y);
            acc += (f0 + f1) + (f2 + f3);
        }
        for (; e < end; ++e) {
            uint2 u = srt[e];
            acc += feat[u.x * DIM + lane] * __uint_as_float(u.y);
        }
        float o = bv;
#pragma unroll
        for (int k = 0; k < DIM; ++k)
            o = fmaf(__shfl(acc, k, 64), Wreg[k], o);
        out[(long)v * DIM + lane] = o;
    }
}

// ===========================================================================
// Fallback path (round-0 kernels) if workspace is too small
// ===========================================================================

__global__ void zero_kernel(float4* __restrict__ p, int n4) {
    int stride = gridDim.x * blockDim.x;
    for (int i = blockIdx.x * blockDim.x + threadIdx.x; i < n4; i += stride)
        p[i] = float4{0.f, 0.f, 0.f, 0.f};
}

__global__ void scatter_kernel(const float* __restrict__ feat,
                               const float* __restrict__ edge_w,
                               const int* __restrict__ src,
                               const int* __restrict__ dst,
                               float* __restrict__ h, int n_edges) {
    int lane = threadIdx.x & 63;
    int wave = (int)((blockIdx.x * blockDim.x + threadIdx.x) >> 6);
    int total_waves = (int)((gridDim.x * blockDim.x) >> 6);
    for (int e = wave; e < n_edges; e += total_waves) {
        int s = src[e], d = dst[e];
        float v = feat[(long)s * DIM + lane] * edge_w[e];
        atomicAdd(&h[(long)d * DIM + lane], v);
    }
}

__global__ void linear_kernel(float* __restrict__ h, const float* __restrict__ W,
                              const float* __restrict__ bias, int n_nodes) {
    __shared__ float Ws[DIM * DIM];
    __shared__ float bs[DIM];
    for (int i = threadIdx.x; i < DIM * DIM; i += blockDim.x) Ws[i] = W[i];
    if (threadIdx.x < DIM) bs[threadIdx.x] = bias[threadIdx.x];
    __syncthreads();
    int lane = threadIdx.x & 63;
    int gwave = blockIdx.x * (blockDim.x >> 6) + (threadIdx.x >> 6);
    int total_waves = gridDim.x * (blockDim.x >> 6);
    for (int row = gwave; row < n_nodes; row += total_waves) {
        float hval = h[(long)row * DIM + lane];
        float acc = bs[lane];
#pragma unroll
        for (int k = 0; k < DIM; ++k)
            acc = fmaf(__shfl(hval, k, 64), Ws[k * DIM + lane], acc);
        h[(long)row * DIM + lane] = acc;
    }
}

// ===========================================================================
extern "C" void kernel_launch(void* const* d_in, const int* in_sizes, int n_in,
                              void* d_out, int out_size, void* d_ws, size_t ws_size,
                              hipStream_t stream) {
    const float* feat   = (const float*)d_in[0];
    const float* edge_w = (const float*)d_in[1];
    const int*   src    = (const int*)d_in[2];
    const int*   dst    = (const int*)d_in[3];
    const float* weight = (const float*)d_in[4];
    const float* bias   = (const float*)d_in[5];
    float* out = (float*)d_out;

    // ws layout: srt[E] (uint2) | cnt[N] | off[N+1] | cursor[N] | partials[64]
    size_t needed = (size_t)N_EDGES * 8
                  + (size_t)N_NODES * 4            // cnt
                  + (size_t)(N_NODES + 1) * 4      // off
                  + (size_t)N_NODES * 4            // cursor
                  + 64 * 4;                        // partials
    if (ws_size >= needed) {
        uint2*    srt      = (uint2*)d_ws;
        unsigned* cnt      = (unsigned*)((char*)d_ws + (size_t)N_EDGES * 8);
        unsigned* off      = cnt + N_NODES;
        unsigned* cursor   = off + N_NODES + 1;
        unsigned* partials = cursor + N_NODES;

        zero_u32<<<(N_NODES + 255) / 256, 256, 0, stream>>>(cnt, N_NODES);
        hist_kernel<<<1024, 256, 0, stream>>>(dst, cnt);
        scan1_kernel<<<NSCAN, 1024, 0, stream>>>(cnt, off, partials);
        scan2_kernel<<<1, 64, 0, stream>>>(partials);
        scan3_kernel<<<(N_NODES + 256) / 256, 256, 0, stream>>>(off, partials, cursor);
        scatter_sort_kernel<<<1024, 256, 0, stream>>>(src, dst, edge_w, cursor, srt);
        pull_kernel<<<2048, 256, 0, stream>>>(feat, srt, off, weight, bias, out);
    } else {
        int n4 = N_NODES * DIM / 4;
        zero_kernel<<<2048, 256, 0, stream>>>((float4*)out, n4);
        scatter_kernel<<<2048, 256, 0, stream>>>(feat, edge_w, src, dst, out, N_EDGES);
        linear_kernel<<<2048, 256, 0, stream>>>(out, weight, bias, N_NODES);
    }
}

// Round 5
// 276.912 us; speedup vs baseline: 3.1420x; 1.3437x over previous
//
#include <hip/hip_runtime.h>

#define N_NODES 100000
#define N_EDGES 1600000
#define DIM 64

#define SCAN_BLK 2048
#define NSCAN ((N_NODES + 1 + SCAN_BLK - 1) / SCAN_BLK)   // 49 blocks

#define NSLICE 8
#define SLICE_NODES ((N_NODES + NSLICE - 1) / NSLICE)     // 12500 nodes/slice

// ===========================================================================
// CSR pull path: hist -> scan -> XCD-sliced sort -> fused pull+linear
// ===========================================================================

__global__ void zero_u32(unsigned* __restrict__ p, int n) {
    int i = blockIdx.x * blockDim.x + threadIdx.x;
    if (i < n) p[i] = 0u;
}

// Per-node degree histogram: 1.6M atomics over 100K counters (~16/counter).
__global__ void hist_kernel(const int* __restrict__ dst, unsigned* __restrict__ cnt) {
    int stride = gridDim.x * blockDim.x;
    for (int e = blockIdx.x * blockDim.x + threadIdx.x; e < N_EDGES; e += stride)
        atomicAdd(&cnt[dst[e]], 1u);
}

// Block-local inclusive scan (2048/block) -> exclusive within block + partials.
__global__ void scan1_kernel(const unsigned* __restrict__ cnt,
                             unsigned* __restrict__ off,
                             unsigned* __restrict__ partials) {
    __shared__ unsigned s[SCAN_BLK];
    int t = threadIdx.x;
    int base = blockIdx.x * SCAN_BLK;
    int i0 = base + t, i1 = base + t + 1024;
    s[t]        = (i0 < N_NODES) ? cnt[i0] : 0u;
    s[t + 1024] = (i1 < N_NODES) ? cnt[i1] : 0u;
    __syncthreads();
    for (int o = 1; o < SCAN_BLK; o <<= 1) {
        unsigned a0 = s[t];
        unsigned a1 = s[t + 1024];
        unsigned b0 = (t >= o) ? s[t - o] : 0u;
        unsigned b1 = (t + 1024 >= o) ? s[t + 1024 - o] : 0u;
        __syncthreads();
        s[t] = a0 + b0;
        s[t + 1024] = a1 + b1;
        __syncthreads();
    }
    for (int i = t; i < SCAN_BLK; i += 1024) {
        int g = base + i;
        if (g <= N_NODES) off[g] = (i == 0) ? 0u : s[i - 1];
    }
    if (t == 0) partials[blockIdx.x] = s[SCAN_BLK - 1];
}

// Serial exclusive scan of the 49 block partials.
__global__ void scan2_kernel(unsigned* __restrict__ partials) {
    if (threadIdx.x == 0 && blockIdx.x == 0) {
        unsigned run = 0;
        for (int b = 0; b < NSCAN; ++b) {
            unsigned v = partials[b];
            partials[b] = run;
            run += v;
        }
    }
}

// Add block offsets; init cursor = off.
__global__ void scan3_kernel(unsigned* __restrict__ off,
                             const unsigned* __restrict__ partials,
                             unsigned* __restrict__ cursor) {
    int i = blockIdx.x * blockDim.x + threadIdx.x;
    if (i <= N_NODES) {
        unsigned v = off[i] + partials[i / SCAN_BLK];
        off[i] = v;
        if (i < N_NODES) cursor[i] = v;
    }
}

// XCD-sliced scatter: block handles dst-slice (blockIdx%8) x edge-chunk
// (blockIdx/8). Cursor atomics + srt writes stay inside one XCD's L2
// (1.6 MB window); edge reads are 8x-amplified but L3-served.
__global__ void scatter_sort_kernel(const int* __restrict__ src,
                                    const int* __restrict__ dst,
                                    const float* __restrict__ w,
                                    unsigned* __restrict__ cursor,
                                    uint2* __restrict__ srt) {
    int slice = blockIdx.x & (NSLICE - 1);
    int chunk = blockIdx.x >> 3;
    int nchunks = gridDim.x >> 3;
    int lo = slice * SLICE_NODES;
    int hi = lo + SLICE_NODES; if (hi > N_NODES) hi = N_NODES;
    int per = (N_EDGES + nchunks - 1) / nchunks;
    int e0 = chunk * per;
    int e1 = e0 + per; if (e1 > N_EDGES) e1 = N_EDGES;
    for (int e = e0 + threadIdx.x; e < e1; e += blockDim.x) {
        int d = dst[e];
        if (d >= lo && d < hi) {
            unsigned pos = atomicAdd(&cursor[d], 1u);
            srt[pos] = make_uint2((unsigned)src[e], __float_as_uint(w[e]));
        }
    }
}

// One wave per node. Cooperative edge fetch: lane l loads edge beg+l's
// {src,w} in one coalesced access, then shfl-broadcast; all gathers issue
// back-to-back (high MLP, no uniform-load round trip per group).
// W in LDS as packed column-pairs (float2), bias in LDS.
__global__ __launch_bounds__(256) void pull_kernel(
        const float* __restrict__ feat, const uint2* __restrict__ srt,
        const unsigned* __restrict__ off, const float* __restrict__ W,
        const float* __restrict__ bias, float* __restrict__ out) {
    __shared__ float2 Ws2[(DIM / 2) * DIM];   // [k2][lane] = {W[2k2][lane], W[2k2+1][lane]}
    __shared__ float bs[DIM];
    int tid = threadIdx.x;
    for (int i = tid; i < (DIM / 2) * DIM; i += 256) {
        int k2 = i >> 6, ln = i & 63;
        Ws2[i] = make_float2(W[(2 * k2) * DIM + ln], W[(2 * k2 + 1) * DIM + ln]);
    }
    if (tid < DIM) bs[tid] = bias[tid];
    __syncthreads();

    int lane = tid & 63;
    int gwave = (int)((blockIdx.x * blockDim.x + tid) >> 6);
    int nwaves = (int)((gridDim.x * blockDim.x) >> 6);

    for (int v = gwave; v < N_NODES; v += nwaves) {
        int beg = (int)off[v], end = (int)off[v + 1];
        float acc = 0.f;
        int base = beg;
        int deg = end - beg;
        while (deg > 0) {
            int cnt = deg < 64 ? deg : 64;
            uint2 u = make_uint2(0u, 0u);
            if (lane < cnt) u = srt[base + lane];
            unsigned su = u.x;
            float    wu = __uint_as_float(u.y);

            int k = 0;
            for (; k + 8 <= cnt; k += 8) {
                unsigned s0 = __shfl(su, k + 0); float w0 = __shfl(wu, k + 0);
                unsigned s1 = __shfl(su, k + 1); float w1 = __shfl(wu, k + 1);
                unsigned s2 = __shfl(su, k + 2); float w2 = __shfl(wu, k + 2);
                unsigned s3 = __shfl(su, k + 3); float w3 = __shfl(wu, k + 3);
                unsigned s4 = __shfl(su, k + 4); float w4 = __shfl(wu, k + 4);
                unsigned s5 = __shfl(su, k + 5); float w5 = __shfl(wu, k + 5);
                unsigned s6 = __shfl(su, k + 6); float w6 = __shfl(wu, k + 6);
                unsigned s7 = __shfl(su, k + 7); float w7 = __shfl(wu, k + 7);
                float f0 = feat[s0 * DIM + lane];
                float f1 = feat[s1 * DIM + lane];
                float f2 = feat[s2 * DIM + lane];
                float f3 = feat[s3 * DIM + lane];
                float f4 = feat[s4 * DIM + lane];
                float f5 = feat[s5 * DIM + lane];
                float f6 = feat[s6 * DIM + lane];
                float f7 = feat[s7 * DIM + lane];
                float a0 = fmaf(f0, w0, fmaf(f1, w1, 0.f));
                float a1 = fmaf(f2, w2, fmaf(f3, w3, 0.f));
                float a2 = fmaf(f4, w4, fmaf(f5, w5, 0.f));
                float a3 = fmaf(f6, w6, fmaf(f7, w7, 0.f));
                acc += (a0 + a1) + (a2 + a3);
            }
            for (; k < cnt; ++k) {
                unsigned s0 = __shfl(su, k); float w0 = __shfl(wu, k);
                acc = fmaf(feat[s0 * DIM + lane], w0, acc);
            }
            base += cnt;
            deg -= cnt;
        }

        // linear: out[v][lane] = sum_k h[k] * W[k][lane] + b[lane]
        float o = bs[lane];
#pragma unroll
        for (int k2 = 0; k2 < DIM / 2; ++k2) {
            float2 wp = Ws2[k2 * DIM + lane];
            o = fmaf(__shfl(acc, 2 * k2 + 0, 64), wp.x, o);
            o = fmaf(__shfl(acc, 2 * k2 + 1, 64), wp.y, o);
        }
        out[(long)v * DIM + lane] = o;
    }
}

// ===========================================================================
// Fallback path (round-0 kernels) if workspace is too small
// ===========================================================================

__global__ void zero_kernel(float4* __restrict__ p, int n4) {
    int stride = gridDim.x * blockDim.x;
    for (int i = blockIdx.x * blockDim.x + threadIdx.x; i < n4; i += stride)
        p[i] = float4{0.f, 0.f, 0.f, 0.f};
}

__global__ void scatter_kernel(const float* __restrict__ feat,
                               const float* __restrict__ edge_w,
                               const int* __restrict__ src,
                               const int* __restrict__ dst,
                               float* __restrict__ h, int n_edges) {
    int lane = threadIdx.x & 63;
    int wave = (int)((blockIdx.x * blockDim.x + threadIdx.x) >> 6);
    int total_waves = (int)((gridDim.x * blockDim.x) >> 6);
    for (int e = wave; e < n_edges; e += total_waves) {
        int s = src[e], d = dst[e];
        float v = feat[(long)s * DIM + lane] * edge_w[e];
        atomicAdd(&h[(long)d * DIM + lane], v);
    }
}

__global__ void linear_kernel(float* __restrict__ h, const float* __restrict__ W,
                              const float* __restrict__ bias, int n_nodes) {
    __shared__ float Ws[DIM * DIM];
    __shared__ float bs[DIM];
    for (int i = threadIdx.x; i < DIM * DIM; i += blockDim.x) Ws[i] = W[i];
    if (threadIdx.x < DIM) bs[threadIdx.x] = bias[threadIdx.x];
    __syncthreads();
    int lane = threadIdx.x & 63;
    int gwave = blockIdx.x * (blockDim.x >> 6) + (threadIdx.x >> 6);
    int total_waves = gridDim.x * (blockDim.x >> 6);
    for (int row = gwave; row < n_nodes; row += total_waves) {
        float hval = h[(long)row * DIM + lane];
        float acc = bs[lane];
#pragma unroll
        for (int k = 0; k < DIM; ++k)
            acc = fmaf(__shfl(hval, k, 64), Ws[k * DIM + lane], acc);
        h[(long)row * DIM + lane] = acc;
    }
}

// ===========================================================================
extern "C" void kernel_launch(void* const* d_in, const int* in_sizes, int n_in,
                              void* d_out, int out_size, void* d_ws, size_t ws_size,
                              hipStream_t stream) {
    const float* feat   = (const float*)d_in[0];
    const float* edge_w = (const float*)d_in[1];
    const int*   src    = (const int*)d_in[2];
    const int*   dst    = (const int*)d_in[3];
    const float* weight = (const float*)d_in[4];
    const float* bias   = (const float*)d_in[5];
    float* out = (float*)d_out;

    // ws layout: srt[E] (uint2) | cnt[N] | off[N+1] | cursor[N] | partials[64]
    size_t needed = (size_t)N_EDGES * 8
                  + (size_t)N_NODES * 4            // cnt
                  + (size_t)(N_NODES + 1) * 4      // off
                  + (size_t)N_NODES * 4            // cursor
                  + 64 * 4;                        // partials
    if (ws_size >= needed) {
        uint2*    srt      = (uint2*)d_ws;
        unsigned* cnt      = (unsigned*)((char*)d_ws + (size_t)N_EDGES * 8);
        unsigned* off      = cnt + N_NODES;
        unsigned* cursor   = off + N_NODES + 1;
        unsigned* partials = cursor + N_NODES;

        zero_u32<<<(N_NODES + 255) / 256, 256, 0, stream>>>(cnt, N_NODES);
        hist_kernel<<<1024, 256, 0, stream>>>(dst, cnt);
        scan1_kernel<<<NSCAN, 1024, 0, stream>>>(cnt, off, partials);
        scan2_kernel<<<1, 64, 0, stream>>>(partials);
        scan3_kernel<<<(N_NODES + 256) / 256, 256, 0, stream>>>(off, partials, cursor);
        scatter_sort_kernel<<<2048, 256, 0, stream>>>(src, dst, edge_w, cursor, srt);
        pull_kernel<<<2048, 256, 0, stream>>>(feat, srt, off, weight, bias, out);
    } else {
        int n4 = N_NODES * DIM / 4;
        zero_kernel<<<2048, 256, 0, stream>>>((float4*)out, n4);
        scatter_kernel<<<2048, 256, 0, stream>>>(feat, edge_w, src, dst, out, N_EDGES);
        linear_kernel<<<2048, 256, 0, stream>>>(out, weight, bias, N_NODES);
    }
}